// Round 1
// baseline (535.126 us; speedup 1.0000x reference)
//
#include <hip/hip_runtime.h>
#include <hip/hip_bf16.h>

#define N_TOTAL 384
#define BS 128
#define PD 8
#define D_FEAT 131072
#define EPS 1e-6f
#define KC 2048
#define NKCH (D_FEAT / KC)   // 64

typedef __attribute__((ext_vector_type(4))) float f32x4;
typedef __attribute__((ext_vector_type(8))) __bf16 bf16x8;

__device__ __forceinline__ bf16x8 cvt8(const float* p) {
    const float4 lo = *(const float4*)(p);
    const float4 hi = *(const float4*)(p + 4);
    bf16x8 r;
    r[0] = (__bf16)lo.x; r[1] = (__bf16)lo.y; r[2] = (__bf16)lo.z; r[3] = (__bf16)lo.w;
    r[4] = (__bf16)hi.x; r[5] = (__bf16)hi.y; r[6] = (__bf16)hi.z; r[7] = (__bf16)hi.w;
    return r;
}

// G[i][j] = sum_k bf16(X[i][k]) * bf16(X[j][k]), fp32 accumulate.
// grid = 9 tiles * NKCH k-chunks; block = 256 (4 waves, 2x2 of 64x64).
__global__ __launch_bounds__(256) void gram_kernel(const float* __restrict__ X,
                                                   float* __restrict__ G) {
    const int bx   = blockIdx.x;
    const int tile = bx % 9;
    const int kc   = bx / 9;
    const int ti   = (tile % 3) * 128;
    const int tj   = (tile / 3) * 128;
    const int wave = threadIdx.x >> 6;
    const int lane = threadIdx.x & 63;
    const int wr   = (wave >> 1) * 64;
    const int wc   = (wave & 1) * 64;
    const int r16  = lane & 15;
    const int kg   = lane >> 4;

    const size_t kbase = (size_t)kc * KC + (size_t)kg * 8;
    const float* pa[4];
    const float* pb[4];
#pragma unroll
    for (int m = 0; m < 4; m++) {
        pa[m] = X + (size_t)(ti + wr + m * 16 + r16) * D_FEAT + kbase;
        pb[m] = X + (size_t)(tj + wc + m * 16 + r16) * D_FEAT + kbase;
    }

    f32x4 acc[4][4];
#pragma unroll
    for (int m = 0; m < 4; m++)
#pragma unroll
        for (int n = 0; n < 4; n++) acc[m][n] = (f32x4)(0.0f);

    for (int kk = 0; kk < KC; kk += 32) {
        bf16x8 a[4], b[4];
#pragma unroll
        for (int m = 0; m < 4; m++) { a[m] = cvt8(pa[m]); pa[m] += 32; }
#pragma unroll
        for (int m = 0; m < 4; m++) { b[m] = cvt8(pb[m]); pb[m] += 32; }
#pragma unroll
        for (int m = 0; m < 4; m++)
#pragma unroll
            for (int n = 0; n < 4; n++)
                acc[m][n] = __builtin_amdgcn_mfma_f32_16x16x32_bf16(a[m], b[n], acc[m][n], 0, 0, 0);
    }

    // C/D layout (verified on gfx950): col = lane&15, row = (lane>>4)*4 + r
    const int crow = (lane >> 4) * 4;
    const int ccol = lane & 15;
#pragma unroll
    for (int m = 0; m < 4; m++)
#pragma unroll
        for (int n = 0; n < 4; n++)
#pragma unroll
            for (int r = 0; r < 4; r++)
                atomicAdd(&G[(size_t)(ti + wr + m * 16 + crow + r) * N_TOTAL +
                             (tj + wc + n * 16 + ccol)],
                          acc[m][n][r]);
}

// den[i] = sum over j with j%8 != i%8 of exp(10 * cos(i,j)).
// Norms taken from Gram diagonal (consistent with bf16 numerator).
__global__ __launch_bounds__(128) void den_kernel(const float* __restrict__ G,
                                                  float* __restrict__ den) {
    const int i = blockIdx.x;
    __shared__ float sInv[N_TOTAL];
    for (int j = threadIdx.x; j < N_TOTAL; j += 128) {
        const float n = sqrtf(G[(size_t)j * N_TOTAL + j]);
        sInv[j] = 1.0f / fmaxf(n, EPS);
    }
    __syncthreads();

    const float mi  = sInv[i] * 10.0f;   // 1/temp = 10
    const int   myc = i & 7;
    float s = 0.0f;
    for (int j = threadIdx.x; j < N_TOTAL; j += 128) {
        if ((j & 7) != myc)
            s += expf(G[(size_t)i * N_TOTAL + j] * mi * sInv[j]);
    }
#pragma unroll
    for (int off = 32; off > 0; off >>= 1) s += __shfl_down(s, off, 64);
    __shared__ float partial[2];
    if ((threadIdx.x & 63) == 0) partial[threadIdx.x >> 6] = s;
    __syncthreads();
    if (threadIdx.x == 0) den[i] = partial[0] + partial[1];
}

__global__ __launch_bounds__(256) void loss_kernel(const float* __restrict__ G,
                                                   const float* __restrict__ den,
                                                   float* __restrict__ out) {
    __shared__ float sInv[N_TOTAL];
    for (int j = threadIdx.x; j < N_TOTAL; j += 256) {
        const float n = sqrtf(G[(size_t)j * N_TOTAL + j]);
        sInv[j] = 1.0f / fmaxf(n, EPS);
    }
    __syncthreads();

    float s = 0.0f;
    for (int idx = threadIdx.x; idx < 7 * BS; idx += 256) {
        const int p   = idx & (BS - 1);
        const int set = idx >> 7;
        int a, b;
        switch (set) {
            case 0:  a = p;                        b = BS + p;                      break;
            case 1:  a = (p + PD) % N_TOTAL;       b = (BS + p + PD) % N_TOTAL;     break;
            case 2:  a = p;                        b = (p + PD) % N_TOTAL;          break;
            case 3:  a = BS + p;                   b = (BS + p + PD) % N_TOTAL;     break;
            case 4:  a = 2 * BS + p;               b = (2 * BS + p + PD) % N_TOTAL; break;
            case 5:  a = BS + p;                   b = 2 * BS + p;                  break;
            default: a = (BS + p + PD) % N_TOTAL;  b = (2 * BS + p + PD) % N_TOTAL; break;
        }
        const float en = expf(G[(size_t)a * N_TOTAL + b] * sInv[a] * sInv[b] * 10.0f);
        s += log1pf(den[a] / en) + log1pf(den[b] / en);
    }
#pragma unroll
    for (int off = 32; off > 0; off >>= 1) s += __shfl_down(s, off, 64);
    __shared__ float partial[4];
    if ((threadIdx.x & 63) == 0) partial[threadIdx.x >> 6] = s;
    __syncthreads();
    if (threadIdx.x == 0)
        out[0] = (partial[0] + partial[1] + partial[2] + partial[3]) / 768.0f;
}

extern "C" void kernel_launch(void* const* d_in, const int* in_sizes, int n_in,
                              void* d_out, int out_size, void* d_ws, size_t ws_size,
                              hipStream_t stream) {
    (void)in_sizes; (void)n_in; (void)out_size; (void)ws_size;
    const float* X   = (const float*)d_in[0];
    float*       out = (float*)d_out;
    float*       G   = (float*)d_ws;                       // 384*384 fp32
    float*       den = G + (size_t)N_TOTAL * N_TOTAL;      // 384 fp32

    hipMemsetAsync(G, 0, (size_t)N_TOTAL * N_TOTAL * sizeof(float), stream);
    gram_kernel<<<9 * NKCH, 256, 0, stream>>>(X, G);
    den_kernel<<<N_TOTAL, 128, 0, stream>>>(G, den);
    loss_kernel<<<1, 256, 0, stream>>>(G, den, out);
}

// Round 2
// 301.958 us; speedup vs baseline: 1.7722x; 1.7722x over previous
//
#include <hip/hip_runtime.h>
#include <hip/hip_bf16.h>

#define N_TOTAL 384
#define BS 128
#define PD 8
#define D_FEAT 131072
#define EPS 1e-6f
#define KC 1024
#define NKCH (D_FEAT / KC)   // 128
#define N_TILES 6            // upper-triangular 128x128 tiles of the 3x3 grid

typedef __attribute__((ext_vector_type(4))) float f32x4;
typedef __attribute__((ext_vector_type(8))) __bf16 bf16x8;

__device__ __forceinline__ bf16x8 cvt8(const float* p) {
    const float4 lo = *(const float4*)(p);
    const float4 hi = *(const float4*)(p + 4);
    bf16x8 r;
    r[0] = (__bf16)lo.x; r[1] = (__bf16)lo.y; r[2] = (__bf16)lo.z; r[3] = (__bf16)lo.w;
    r[4] = (__bf16)hi.x; r[5] = (__bf16)hi.y; r[6] = (__bf16)hi.z; r[7] = (__bf16)hi.w;
    return r;
}

// Symmetric accessor: only upper-triangular 128-tiles of G are populated.
__device__ __forceinline__ float gsym(const float* __restrict__ G, int i, int j) {
    return ((i >> 7) <= (j >> 7)) ? G[(size_t)i * N_TOTAL + j]
                                  : G[(size_t)j * N_TOTAL + i];
}

// G[i][j] = sum_k bf16(X[i][k]) * bf16(X[j][k]), fp32 accumulate.
// grid = N_TILES (fast dim, for column-stripe L2/L3 sharing) * NKCH.
// block = 256 (4 waves, 2x2 of 64x64).
__global__ __launch_bounds__(256) void gram_kernel(const float* __restrict__ X,
                                                   float* __restrict__ G) {
    const int bx   = blockIdx.x;
    const int tile = bx % N_TILES;
    const int kc   = bx / N_TILES;
    // upper-tri tile list: (0,0)(0,1)(0,2)(1,1)(1,2)(2,2)
    const int ti = (tile < 3) ? 0 : (tile < 5 ? 128 : 256);
    const int tj = (tile == 0) ? 0
                 : (tile == 1 || tile == 3) ? 128
                 : 256;

    const int wave = threadIdx.x >> 6;
    const int lane = threadIdx.x & 63;
    const int wr   = (wave >> 1) * 64;
    const int wc   = (wave & 1) * 64;
    const int r16  = lane & 15;
    const int kg   = lane >> 4;

    const size_t kbase = (size_t)kc * KC + (size_t)kg * 8;
    const float* pa[4];
    const float* pb[4];
#pragma unroll
    for (int m = 0; m < 4; m++) {
        pa[m] = X + (size_t)(ti + wr + m * 16 + r16) * D_FEAT + kbase;
        pb[m] = X + (size_t)(tj + wc + m * 16 + r16) * D_FEAT + kbase;
    }

    f32x4 acc[4][4];
#pragma unroll
    for (int m = 0; m < 4; m++)
#pragma unroll
        for (int n = 0; n < 4; n++) acc[m][n] = (f32x4)(0.0f);

    for (int kk = 0; kk < KC; kk += 32) {
        bf16x8 a[4], b[4];
#pragma unroll
        for (int m = 0; m < 4; m++) { a[m] = cvt8(pa[m]); pa[m] += 32; }
#pragma unroll
        for (int m = 0; m < 4; m++) { b[m] = cvt8(pb[m]); pb[m] += 32; }
#pragma unroll
        for (int m = 0; m < 4; m++)
#pragma unroll
            for (int n = 0; n < 4; n++)
                acc[m][n] = __builtin_amdgcn_mfma_f32_16x16x32_bf16(a[m], b[n], acc[m][n], 0, 0, 0);
    }

    // C/D layout (verified on gfx950): col = lane&15, row = (lane>>4)*4 + r
    const int crow = (lane >> 4) * 4;
    const int ccol = lane & 15;
#pragma unroll
    for (int m = 0; m < 4; m++)
#pragma unroll
        for (int n = 0; n < 4; n++)
#pragma unroll
            for (int r = 0; r < 4; r++)
                atomicAdd(&G[(size_t)(ti + wr + m * 16 + crow + r) * N_TOTAL +
                             (tj + wc + n * 16 + ccol)],
                          acc[m][n][r]);
}

// den[i] = sum over j with j%8 != i%8 of exp(10 * cos(i,j)).
// Norms taken from Gram diagonal (consistent with bf16 numerator).
__global__ __launch_bounds__(128) void den_kernel(const float* __restrict__ G,
                                                  float* __restrict__ den) {
    const int i = blockIdx.x;
    __shared__ float sInv[N_TOTAL];
    for (int j = threadIdx.x; j < N_TOTAL; j += 128) {
        const float n = sqrtf(G[(size_t)j * N_TOTAL + j]);
        sInv[j] = 1.0f / fmaxf(n, EPS);
    }
    __syncthreads();

    const float mi  = sInv[i] * 10.0f;   // 1/temp = 10
    const int   myc = i & 7;
    float s = 0.0f;
    for (int j = threadIdx.x; j < N_TOTAL; j += 128) {
        if ((j & 7) != myc)
            s += expf(gsym(G, i, j) * mi * sInv[j]);
    }
#pragma unroll
    for (int off = 32; off > 0; off >>= 1) s += __shfl_down(s, off, 64);
    __shared__ float partial[2];
    if ((threadIdx.x & 63) == 0) partial[threadIdx.x >> 6] = s;
    __syncthreads();
    if (threadIdx.x == 0) den[i] = partial[0] + partial[1];
}

__global__ __launch_bounds__(256) void loss_kernel(const float* __restrict__ G,
                                                   const float* __restrict__ den,
                                                   float* __restrict__ out) {
    __shared__ float sInv[N_TOTAL];
    for (int j = threadIdx.x; j < N_TOTAL; j += 256) {
        const float n = sqrtf(G[(size_t)j * N_TOTAL + j]);
        sInv[j] = 1.0f / fmaxf(n, EPS);
    }
    __syncthreads();

    float s = 0.0f;
    for (int idx = threadIdx.x; idx < 7 * BS; idx += 256) {
        const int p   = idx & (BS - 1);
        const int set = idx >> 7;
        int a, b;
        switch (set) {
            case 0:  a = p;                        b = BS + p;                      break;
            case 1:  a = (p + PD) % N_TOTAL;       b = (BS + p + PD) % N_TOTAL;     break;
            case 2:  a = p;                        b = (p + PD) % N_TOTAL;          break;
            case 3:  a = BS + p;                   b = (BS + p + PD) % N_TOTAL;     break;
            case 4:  a = 2 * BS + p;               b = (2 * BS + p + PD) % N_TOTAL; break;
            case 5:  a = BS + p;                   b = 2 * BS + p;                  break;
            default: a = (BS + p + PD) % N_TOTAL;  b = (2 * BS + p + PD) % N_TOTAL; break;
        }
        const float en = expf(gsym(G, a, b) * sInv[a] * sInv[b] * 10.0f);
        s += log1pf(den[a] / en) + log1pf(den[b] / en);
    }
#pragma unroll
    for (int off = 32; off > 0; off >>= 1) s += __shfl_down(s, off, 64);
    __shared__ float partial[4];
    if ((threadIdx.x & 63) == 0) partial[threadIdx.x >> 6] = s;
    __syncthreads();
    if (threadIdx.x == 0)
        out[0] = (partial[0] + partial[1] + partial[2] + partial[3]) / 768.0f;
}

extern "C" void kernel_launch(void* const* d_in, const int* in_sizes, int n_in,
                              void* d_out, int out_size, void* d_ws, size_t ws_size,
                              hipStream_t stream) {
    (void)in_sizes; (void)n_in; (void)out_size; (void)ws_size;
    const float* X   = (const float*)d_in[0];
    float*       out = (float*)d_out;
    float*       G   = (float*)d_ws;                       // 384*384 fp32
    float*       den = G + (size_t)N_TOTAL * N_TOTAL;      // 384 fp32

    hipMemsetAsync(G, 0, (size_t)N_TOTAL * N_TOTAL * sizeof(float), stream);
    gram_kernel<<<N_TILES * NKCH, 256, 0, stream>>>(X, G);
    den_kernel<<<N_TOTAL, 128, 0, stream>>>(G, den);
    loss_kernel<<<1, 256, 0, stream>>>(G, den, out);
}